// Round 3
// baseline (2656.520 us; speedup 1.0000x reference)
//
#include <hip/hip_runtime.h>

typedef unsigned short u16;
typedef unsigned int   u32;
typedef __bf16 bf16x8 __attribute__((ext_vector_type(8)));
typedef float  f32x4  __attribute__((ext_vector_type(4)));

#define B_  8
#define T_  2048
#define D_  1024
#define H_  8
#define C_  64
#define DV_ 128
#define M_  (B_*T_)   // 16384
#define L_  128       // scan chunk length
#define NC_ (T_/L_)   // 16 chunks
#define TS_ 8         // timesteps per LDS sub-block

__device__ __forceinline__ u16 f2bf(float f){
  u32 u = __float_as_uint(f);
  u32 r = (u + 0x7fffu + ((u >> 16) & 1u)) >> 16;   // RNE
  return (u16)r;
}
__device__ __forceinline__ float bf2f(u16 u){
  return __uint_as_float(((u32)u) << 16);
}

// ---------------- LayerNorm: x (M,1024) f32 -> xn bf16 ----------------
__global__ __launch_bounds__(256) void ln_kernel(
    const float* __restrict__ x, const float* __restrict__ gamma,
    const float* __restrict__ beta, u16* __restrict__ xnb){
  const int m = blockIdx.x;
  const int tid = threadIdx.x;
  const int wave = tid >> 6, lane = tid & 63;
  const float* xr = x + (size_t)m * D_;
  float4 xv = *(const float4*)&xr[tid*4];
  float s = xv.x + xv.y + xv.z + xv.w;
  #pragma unroll
  for (int off = 32; off > 0; off >>= 1) s += __shfl_xor(s, off, 64);
  __shared__ float red[8];
  if (lane == 0) red[wave] = s;
  __syncthreads();
  float mu = (red[0]+red[1]+red[2]+red[3]) * (1.f/1024.f);
  float dx = xv.x-mu, dy = xv.y-mu, dz = xv.z-mu, dw = xv.w-mu;
  float ss = dx*dx + dy*dy + dz*dz + dw*dw;
  #pragma unroll
  for (int off = 32; off > 0; off >>= 1) ss += __shfl_xor(ss, off, 64);
  if (lane == 0) red[4+wave] = ss;
  __syncthreads();
  float var = (red[4]+red[5]+red[6]+red[7]) * (1.f/1024.f);
  float rs = rsqrtf(var + 1e-5f);
  float4 g  = *(const float4*)&gamma[tid*4];
  float4 bb = *(const float4*)&beta[tid*4];
  ushort4 o4;
  o4.x = f2bf(dx*rs*g.x + bb.x);
  o4.y = f2bf(dy*rs*g.y + bb.y);
  o4.z = f2bf(dz*rs*g.z + bb.z);
  o4.w = f2bf(dw*rs*g.w + bb.w);
  *(ushort4*)&xnb[(size_t)m*D_ + tid*4] = o4;
}

// ------------- weight prep: convert/concat/transpose to bf16 -------------
__global__ __launch_bounds__(256) void prep_weights(
    const float* __restrict__ Wq, const float* __restrict__ Wk,
    const float* __restrict__ Wv, const float* __restrict__ Wa,
    const float* __restrict__ Qc, const float* __restrict__ Vc,
    const float* __restrict__ Wo,
    u16* __restrict__ Wcatb, u16* __restrict__ QcTb,
    u16* __restrict__ VcTb,  u16* __restrict__ Wob){
  int idx = blockIdx.x * 256 + threadIdx.x;
  if (idx < 720896){                       // 704*1024
    int r = idx >> 10, col = idx & 1023;
    float v;
    if (r < 64)       v = Wq[(size_t)r*1024 + col];
    else if (r < 128) v = Wk[(size_t)(r-64)*1024 + col];
    else if (r < 192) v = Wv[(size_t)(r-128)*1024 + col];
    else              v = Wa[(size_t)(r-192)*1024 + col];
    Wcatb[idx] = f2bf(v);
  } else if (idx < 753664){                // +512*64
    int i = idx - 720896;
    int n = i >> 6, c = i & 63; int h = n >> 6, e = n & 63;
    QcTb[i] = f2bf(Qc[((size_t)h*64 + c)*64 + e]);
  } else if (idx < 819200){                // +1024*64
    int i = idx - 753664;
    int n = i >> 6, c = i & 63; int h = n >> 7, d = n & 127;
    VcTb[i] = f2bf(Vc[((size_t)h*64 + c)*128 + d]);
  } else if (idx < 1867776){               // +1024*1024
    int i = idx - 819200;
    Wob[i] = f2bf(Wo[i]);
  }
}

// ------------- generic bf16 MFMA GEMM: C = A[M,K] @ Bw[N,K]^T (+res) -------
// out: f32 to C (plus optional res) OR bf16 to Cb (if Cb != nullptr)
__global__ __launch_bounds__(256) void gemm_bf16(
    const u16* __restrict__ A, const u16* __restrict__ Bw,
    float* __restrict__ C, const float* __restrict__ res,
    u16* __restrict__ Cb, int N, int K){
  __shared__ u16 As[128][36];
  __shared__ u16 Bs[64][36];
  const int tid = threadIdx.x;
  const int wave = tid >> 6;
  const int lane = tid & 63;
  const int q  = lane >> 4;
  const int mr = lane & 15;
  const int m0 = blockIdx.x * 128;
  const int n0 = blockIdx.y * 64;

  union FragU { u32 u[4]; bf16x8 v; };
  f32x4 zero = {0.f, 0.f, 0.f, 0.f};
  f32x4 acc[2][4];
  #pragma unroll
  for (int i = 0; i < 2; i++)
    #pragma unroll
    for (int j = 0; j < 4; j++) acc[i][j] = zero;

  for (int k0 = 0; k0 < K; k0 += 32){
    #pragma unroll
    for (int p = 0; p < 2; ++p){
      int ch = p*256 + tid;
      int r = ch >> 2, c4 = ch & 3;
      const uint4 val = *(const uint4*)(&A[(size_t)(m0 + r)*K + k0 + c4*8]);
      u32* dst = (u32*)&As[r][c4*8];
      dst[0]=val.x; dst[1]=val.y; dst[2]=val.z; dst[3]=val.w;
    }
    {
      int r = tid >> 2, c4 = tid & 3;
      const uint4 val = *(const uint4*)(&Bw[(size_t)(n0 + r)*K + k0 + c4*8]);
      u32* dst = (u32*)&Bs[r][c4*8];
      dst[0]=val.x; dst[1]=val.y; dst[2]=val.z; dst[3]=val.w;
    }
    __syncthreads();
    bf16x8 afr[2], bfr[4];
    #pragma unroll
    for (int mt = 0; mt < 2; mt++){
      const u32* p = (const u32*)&As[wave*32 + mt*16 + mr][q*8];
      FragU f; f.u[0]=p[0]; f.u[1]=p[1]; f.u[2]=p[2]; f.u[3]=p[3];
      afr[mt] = f.v;
    }
    #pragma unroll
    for (int nt = 0; nt < 4; nt++){
      const u32* p = (const u32*)&Bs[nt*16 + mr][q*8];
      FragU f; f.u[0]=p[0]; f.u[1]=p[1]; f.u[2]=p[2]; f.u[3]=p[3];
      bfr[nt] = f.v;
    }
    #pragma unroll
    for (int mt = 0; mt < 2; mt++)
      #pragma unroll
      for (int nt = 0; nt < 4; nt++)
        acc[mt][nt] = __builtin_amdgcn_mfma_f32_16x16x32_bf16(
            afr[mt], bfr[nt], acc[mt][nt], 0, 0, 0);
    __syncthreads();
  }

  #pragma unroll
  for (int mt = 0; mt < 2; mt++)
    #pragma unroll
    for (int nt = 0; nt < 4; nt++)
      #pragma unroll
      for (int r = 0; r < 4; r++){
        int row = m0 + wave*32 + mt*16 + q*4 + r;
        int col = n0 + nt*16 + mr;
        size_t idx = (size_t)row * N + col;
        float v = acc[mt][nt][r];
        if (res) v += res[idx];
        if (Cb) Cb[idx] = f2bf(v);
        else    C[idx] = v;
      }
}

// ------------- split proj (M x 704) -------------
__global__ __launch_bounds__(256) void split_proj(
    const float* __restrict__ proj, const float* __restrict__ Wab,
    u16* __restrict__ qlatb, float* __restrict__ knf,
    u16* __restrict__ vlatb, float* __restrict__ alphaf){
  const int m = blockIdx.x * 4 + (threadIdx.x >> 6);
  const int lane = threadIdx.x & 63;
  const float* pr = proj + (size_t)m * 704;
  qlatb[(size_t)m*64 + lane] = f2bf(pr[lane]);
  float kv = pr[64 + lane];
  float ss = kv * kv;
  #pragma unroll
  for (int off = 32; off > 0; off >>= 1) ss += __shfl_xor(ss, off, 64);
  float nrm = fmaxf(sqrtf(ss), 1e-12f);
  knf[(size_t)m*64 + lane] = kv / nrm;
  vlatb[(size_t)m*64 + lane] = f2bf(pr[128 + lane]);
  #pragma unroll
  for (int j = 0; j < 8; j++){
    int jj = j*64 + lane;
    float av = pr[192 + jj] + Wab[jj];
    alphaf[(size_t)m*512 + jj] = 1.f / (1.f + expf(-av));
  }
}

// ===================== blocked two-pass gated scan =====================
// pass1: per-chunk local scan from zero -> Sbuf[bh][ch][c][d], btot[bh][ch][c]
// combine: sequential over chunks, IN PLACE: Sbuf[ch] <- prefix state
// pass2: replay chunk scan from Sbuf, emit o (bf16)

__global__ __launch_bounds__(128) void scan_pass1(
    const float* __restrict__ knf, const u16* __restrict__ vb,
    const float* __restrict__ alphaf,
    float* __restrict__ Sbuf, float* __restrict__ btot){
  const int ch = blockIdx.x;        // 0..NC_-2 (last chunk's state unused)
  const int bh = blockIdx.y;
  const int b = bh >> 3, h = bh & 7;
  const int tid = threadIdx.x;
  const int t0 = ch * L_;
  __shared__ __align__(16) float sK[2][TS_][64];
  __shared__ __align__(16) float sA[2][TS_][64];
  __shared__ __align__(16) float sV[2][TS_][128];

  const float* kbase = knf    + ((size_t)(b*T_ + t0))*64;
  const float* abase = alphaf + ((size_t)(b*T_ + t0))*512 + h*64;
  const u16*   vbase = vb     + ((size_t)(b*T_ + t0))*1024 + h*128;

  float S[64];
  #pragma unroll
  for (int c = 0; c < 64; c++) S[c] = 0.f;
  float bt = 1.f;

  const int ts = tid >> 4, c4 = (tid & 15) * 4;   // k/a staging coords
  const int tv = tid >> 5, d4 = (tid & 31) * 4;   // v staging coords
  {
    *(float4*)&sK[0][ts][c4] = *(const float4*)&kbase[(size_t)ts*64 + c4];
    *(float4*)&sA[0][ts][c4] = *(const float4*)&abase[(size_t)ts*512 + c4];
    ushort4 v0 = *(const ushort4*)&vbase[(size_t)tv*1024 + d4];
    ushort4 v1 = *(const ushort4*)&vbase[(size_t)(tv+4)*1024 + d4];
    float4 f0 = {bf2f(v0.x), bf2f(v0.y), bf2f(v0.z), bf2f(v0.w)};
    float4 f1 = {bf2f(v1.x), bf2f(v1.y), bf2f(v1.z), bf2f(v1.w)};
    *(float4*)&sV[0][tv][d4]   = f0;
    *(float4*)&sV[0][tv+4][d4] = f1;
  }
  __syncthreads();

  for (int sb = 0; sb < L_/TS_; sb++){
    const int cur = sb & 1, nxt = cur ^ 1;
    const bool more = (sb + 1 < L_/TS_);
    float4 pk, pa; ushort4 pv0, pv1;
    if (more){
      int tb = (sb+1)*TS_;
      pk  = *(const float4*)&kbase[(size_t)(tb+ts)*64 + c4];
      pa  = *(const float4*)&abase[(size_t)(tb+ts)*512 + c4];
      pv0 = *(const ushort4*)&vbase[(size_t)(tb+tv)*1024 + d4];
      pv1 = *(const ushort4*)&vbase[(size_t)(tb+tv+4)*1024 + d4];
    }
    for (int tt = 0; tt < TS_; tt++){
      const float vd = sV[cur][tt][tid];
      #pragma unroll
      for (int c4i = 0; c4i < 16; c4i++){
        float4 a4 = *(const float4*)&sA[cur][tt][c4i*4];
        float4 k4 = *(const float4*)&sK[cur][tt][c4i*4];
        S[c4i*4+0] = a4.x*S[c4i*4+0] + k4.x*vd;
        S[c4i*4+1] = a4.y*S[c4i*4+1] + k4.y*vd;
        S[c4i*4+2] = a4.z*S[c4i*4+2] + k4.z*vd;
        S[c4i*4+3] = a4.w*S[c4i*4+3] + k4.w*vd;
      }
      if (tid < 64) bt *= sA[cur][tt][tid];
    }
    if (more){
      *(float4*)&sK[nxt][ts][c4] = pk;
      *(float4*)&sA[nxt][ts][c4] = pa;
      float4 f0 = {bf2f(pv0.x), bf2f(pv0.y), bf2f(pv0.z), bf2f(pv0.w)};
      float4 f1 = {bf2f(pv1.x), bf2f(pv1.y), bf2f(pv1.z), bf2f(pv1.w)};
      *(float4*)&sV[nxt][tv][d4]   = f0;
      *(float4*)&sV[nxt][tv+4][d4] = f1;
    }
    __syncthreads();
  }
  float* Sl = Sbuf + ((size_t)bh*NC_ + ch) * (64*128);
  #pragma unroll
  for (int c = 0; c < 64; c++) Sl[(size_t)c*128 + tid] = S[c];
  if (tid < 64) btot[((size_t)bh*NC_ + ch)*64 + tid] = bt;
}

// in-place: Sbuf[ch] (local states) -> Sbuf[ch] (prefix init states)
__global__ __launch_bounds__(256) void scan_combine(
    float* __restrict__ Sbuf, const float* __restrict__ btot){
  const int bh = blockIdx.x;
  const int tid = threadIdx.x;
  float S[32];
  #pragma unroll
  for (int i = 0; i < 32; i++) S[i] = 0.f;
  float*       Sb  = Sbuf + (size_t)bh*NC_*8192;
  const float* btb = btot + (size_t)bh*NC_*64;
  for (int j = 0; j < NC_; j++){
    if (j < NC_-1){
      #pragma unroll
      for (int i = 0; i < 32; i++){
        int e = i*256 + tid;
        float loc = Sb[(size_t)j*8192 + e];          // read local BEFORE overwrite
        float bv  = btb[j*64 + (e >> 7)];
        Sb[(size_t)j*8192 + e] = S[i];               // write prefix state
        S[i] = bv * S[i] + loc;
      }
    } else {
      #pragma unroll
      for (int i = 0; i < 32; i++) Sb[(size_t)j*8192 + i*256 + tid] = S[i];
    }
  }
}

__global__ __launch_bounds__(128) void scan_pass2(
    const float* __restrict__ qf, const float* __restrict__ knf,
    const u16* __restrict__ vb, const float* __restrict__ alphaf,
    const float* __restrict__ Sbuf, u16* __restrict__ ob){
  const int ch = blockIdx.x;        // 0..NC_-1
  const int bh = blockIdx.y;
  const int b = bh >> 3, h = bh & 7;
  const int tid = threadIdx.x;
  const int t0 = ch * L_;
  __shared__ __align__(16) float sQ[2][TS_][64];
  __shared__ __align__(16) float sK[2][TS_][64];
  __shared__ __align__(16) float sA[2][TS_][64];
  __shared__ __align__(16) float sV[2][TS_][128];

  const float* qbase = qf     + ((size_t)(b*T_ + t0))*512 + h*64;
  const float* kbase = knf    + ((size_t)(b*T_ + t0))*64;
  const float* abase = alphaf + ((size_t)(b*T_ + t0))*512 + h*64;
  const u16*   vbase = vb     + ((size_t)(b*T_ + t0))*1024 + h*128;
  u16*         obase = ob     + ((size_t)(b*T_ + t0))*1024 + h*128;

  float S[64];
  const float* Si = Sbuf + ((size_t)bh*NC_ + ch) * (64*128);
  #pragma unroll
  for (int c = 0; c < 64; c++) S[c] = Si[(size_t)c*128 + tid];

  const int ts = tid >> 4, c4 = (tid & 15) * 4;
  const int tv = tid >> 5, d4 = (tid & 31) * 4;
  {
    *(float4*)&sQ[0][ts][c4] = *(const float4*)&qbase[(size_t)ts*512 + c4];
    *(float4*)&sK[0][ts][c4] = *(const float4*)&kbase[(size_t)ts*64 + c4];
    *(float4*)&sA[0][ts][c4] = *(const float4*)&abase[(size_t)ts*512 + c4];
    ushort4 v0 = *(const ushort4*)&vbase[(size_t)tv*1024 + d4];
    ushort4 v1 = *(const ushort4*)&vbase[(size_t)(tv+4)*1024 + d4];
    float4 f0 = {bf2f(v0.x), bf2f(v0.y), bf2f(v0.z), bf2f(v0.w)};
    float4 f1 = {bf2f(v1.x), bf2f(v1.y), bf2f(v1.z), bf2f(v1.w)};
    *(float4*)&sV[0][tv][d4]   = f0;
    *(float4*)&sV[0][tv+4][d4] = f1;
  }
  __syncthreads();

  for (int sb = 0; sb < L_/TS_; sb++){
    const int cur = sb & 1, nxt = cur ^ 1;
    const bool more = (sb + 1 < L_/TS_);
    float4 pq, pk, pa; ushort4 pv0, pv1;
    if (more){
      int tb = (sb+1)*TS_;
      pq  = *(const float4*)&qbase[(size_t)(tb+ts)*512 + c4];
      pk  = *(const float4*)&kbase[(size_t)(tb+ts)*64 + c4];
      pa  = *(const float4*)&abase[(size_t)(tb+ts)*512 + c4];
      pv0 = *(const ushort4*)&vbase[(size_t)(tb+tv)*1024 + d4];
      pv1 = *(const ushort4*)&vbase[(size_t)(tb+tv+4)*1024 + d4];
    }
    for (int tt = 0; tt < TS_; tt++){
      const float vd = sV[cur][tt][tid];
      float o = 0.f;
      #pragma unroll
      for (int c4i = 0; c4i < 16; c4i++){
        float4 a4 = *(const float4*)&sA[cur][tt][c4i*4];
        float4 k4 = *(const float4*)&sK[cur][tt][c4i*4];
        float4 q4 = *(const float4*)&sQ[cur][tt][c4i*4];
        S[c4i*4+0] = a4.x*S[c4i*4+0] + k4.x*vd;  o += S[c4i*4+0]*q4.x;
        S[c4i*4+1] = a4.y*S[c4i*4+1] + k4.y*vd;  o += S[c4i*4+1]*q4.y;
        S[c4i*4+2] = a4.z*S[c4i*4+2] + k4.z*vd;  o += S[c4i*4+2]*q4.z;
        S[c4i*4+3] = a4.w*S[c4i*4+3] + k4.w*vd;  o += S[c4i*4+3]*q4.w;
      }
      obase[(size_t)(sb*TS_+tt)*1024 + tid] = f2bf(o);
    }
    if (more){
      *(float4*)&sQ[nxt][ts][c4] = pq;
      *(float4*)&sK[nxt][ts][c4] = pk;
      *(float4*)&sA[nxt][ts][c4] = pa;
      float4 f0 = {bf2f(pv0.x), bf2f(pv0.y), bf2f(pv0.z), bf2f(pv0.w)};
      float4 f1 = {bf2f(pv1.x), bf2f(pv1.y), bf2f(pv1.z), bf2f(pv1.w)};
      *(float4*)&sV[nxt][tv][d4]   = f0;
      *(float4*)&sV[nxt][tv+4][d4] = f1;
    }
    __syncthreads();
  }
}

// ----------------------------- launch -----------------------------
extern "C" void kernel_launch(void* const* d_in, const int* in_sizes, int n_in,
                              void* d_out, int out_size, void* d_ws, size_t ws_size,
                              hipStream_t stream){
  const float* x     = (const float*)d_in[0];
  const float* Wq    = (const float*)d_in[1];
  const float* Wk    = (const float*)d_in[2];
  const float* Wv    = (const float*)d_in[3];
  const float* Qc    = (const float*)d_in[4];
  const float* Vc    = (const float*)d_in[5];
  const float* Wa_w  = (const float*)d_in[6];
  const float* Wa_b  = (const float*)d_in[7];
  const float* Wo    = (const float*)d_in[8];
  const float* gamma = (const float*)d_in[9];
  const float* beta  = (const float*)d_in[10];
  float* out = (float*)d_out;

  char* ws = (char*)d_ws;
  size_t off = 0;
  auto alloc = [&](size_t bytes) -> void* {
    void* p = ws + off; off += (bytes + 255) & ~(size_t)255; return p;
  };
  // total ws use: ~192.74 MB (round-1's 193.0 MB layout is proven to fit)
  // R1: xnb (bf16 M*1024) -> obuf (bf16 M*1024)
  char* R1 = (char*)alloc((size_t)M_ * 1024 * 2);
  u16*   xnb  = (u16*)R1;
  u16*   obuf = (u16*)R1;
  // R2: proj (f32 M*704) -> qf (f32 M*512)
  char* R2 = (char*)alloc((size_t)M_ * 704 * 4);
  float* proj = (float*)R2;
  float* qf   = (float*)R2;
  float* Sbuf   = (float*)alloc((size_t)64 * NC_ * 8192 * 4);   // 33.5 MB
  u16*   vfb    = (u16*)alloc((size_t)M_ * 1024 * 2);           // v bf16
  float* alphaf = (float*)alloc((size_t)M_ * 512 * 4);
  float* knf    = (float*)alloc((size_t)M_ * 64 * 4);
  u16*   qlatb  = (u16*)alloc((size_t)M_ * 64 * 2);
  u16*   vlatb  = (u16*)alloc((size_t)M_ * 64 * 2);
  u16*   Wcatb  = (u16*)alloc((size_t)704 * 1024 * 2);
  u16*   QcTb   = (u16*)alloc((size_t)512 * 64 * 2);
  u16*   VcTb   = (u16*)alloc((size_t)1024 * 64 * 2);
  u16*   Wob    = (u16*)alloc((size_t)1024 * 1024 * 2);
  float* btotp  = (float*)alloc((size_t)64 * NC_ * 64 * 4);
  (void)ws_size; (void)in_sizes; (void)n_in; (void)out_size;

  ln_kernel<<<dim3(M_), dim3(256), 0, stream>>>(x, gamma, beta, xnb);
  prep_weights<<<dim3(7296), dim3(256), 0, stream>>>(
      Wq, Wk, Wv, Wa_w, Qc, Vc, Wo, Wcatb, QcTb, VcTb, Wob);
  gemm_bf16<<<dim3(M_/128, 704/64), dim3(256), 0, stream>>>(
      xnb, Wcatb, proj, nullptr, nullptr, 704, 1024);
  split_proj<<<dim3(M_/4), dim3(256), 0, stream>>>(
      proj, Wa_b, qlatb, knf, vlatb, alphaf);
  // v = v_lat @ VcT^T : (M,1024) bf16 out (must precede qf overwriting R2? no —
  // qf GEMM writes R2 only after split_proj has finished reading proj)
  gemm_bf16<<<dim3(M_/128, 1024/64), dim3(256), 0, stream>>>(
      vlatb, VcTb, nullptr, nullptr, vfb, 1024, 64);
  // q = q_lat @ QcT^T : (M,512) f32 into R2 (proj dead after split_proj)
  gemm_bf16<<<dim3(M_/128, 512/64), dim3(256), 0, stream>>>(
      qlatb, QcTb, qf, nullptr, nullptr, 512, 64);
  scan_pass1<<<dim3(NC_-1, 64), dim3(128), 0, stream>>>(
      knf, vfb, alphaf, Sbuf, btotp);
  scan_combine<<<dim3(64), dim3(256), 0, stream>>>(Sbuf, btotp);
  scan_pass2<<<dim3(NC_, 64), dim3(128), 0, stream>>>(
      qf, knf, vfb, alphaf, Sbuf, obuf);
  gemm_bf16<<<dim3(M_/128, 1024/64), dim3(256), 0, stream>>>(
      obuf, Wob, out, x, nullptr, 1024, 1024);
}

// Round 4
// 875.239 us; speedup vs baseline: 3.0352x; 3.0352x over previous
//
#include <hip/hip_runtime.h>

typedef unsigned short u16;
typedef unsigned int   u32;
typedef __bf16 bf16x8 __attribute__((ext_vector_type(8)));
typedef float  f32x4  __attribute__((ext_vector_type(4)));

#define B_  8
#define T_  2048
#define D_  1024
#define H_  8
#define C_  64
#define DV_ 128
#define M_  (B_*T_)   // 16384
#define L_  128       // scan chunk length
#define NC_ (T_/L_)   // 16 chunks
#define TS_ 8         // timesteps per LDS sub-block

__device__ __forceinline__ u16 f2bf(float f){
  u32 u = __float_as_uint(f);
  u32 r = (u + 0x7fffu + ((u >> 16) & 1u)) >> 16;   // RNE
  return (u16)r;
}
__device__ __forceinline__ float bf2f(u16 u){
  return __uint_as_float(((u32)u) << 16);
}

// ---------------- LayerNorm: x (M,1024) f32 -> xn bf16 ----------------
__global__ __launch_bounds__(256) void ln_kernel(
    const float* __restrict__ x, const float* __restrict__ gamma,
    const float* __restrict__ beta, u16* __restrict__ xnb){
  const int m = blockIdx.x;
  const int tid = threadIdx.x;
  const int wave = tid >> 6, lane = tid & 63;
  const float* xr = x + (size_t)m * D_;
  float4 xv = *(const float4*)&xr[tid*4];
  float s = xv.x + xv.y + xv.z + xv.w;
  #pragma unroll
  for (int off = 32; off > 0; off >>= 1) s += __shfl_xor(s, off, 64);
  __shared__ float red[8];
  if (lane == 0) red[wave] = s;
  __syncthreads();
  float mu = (red[0]+red[1]+red[2]+red[3]) * (1.f/1024.f);
  float dx = xv.x-mu, dy = xv.y-mu, dz = xv.z-mu, dw = xv.w-mu;
  float ss = dx*dx + dy*dy + dz*dz + dw*dw;
  #pragma unroll
  for (int off = 32; off > 0; off >>= 1) ss += __shfl_xor(ss, off, 64);
  if (lane == 0) red[4+wave] = ss;
  __syncthreads();
  float var = (red[4]+red[5]+red[6]+red[7]) * (1.f/1024.f);
  float rs = rsqrtf(var + 1e-5f);
  float4 g  = *(const float4*)&gamma[tid*4];
  float4 bb = *(const float4*)&beta[tid*4];
  ushort4 o4;
  o4.x = f2bf(dx*rs*g.x + bb.x);
  o4.y = f2bf(dy*rs*g.y + bb.y);
  o4.z = f2bf(dz*rs*g.z + bb.z);
  o4.w = f2bf(dw*rs*g.w + bb.w);
  *(ushort4*)&xnb[(size_t)m*D_ + tid*4] = o4;
}

// ------------- weight prep: convert/concat/transpose to bf16 -------------
__global__ __launch_bounds__(256) void prep_weights(
    const float* __restrict__ Wq, const float* __restrict__ Wk,
    const float* __restrict__ Wv, const float* __restrict__ Wa,
    const float* __restrict__ Qc, const float* __restrict__ Vc,
    const float* __restrict__ Wo,
    u16* __restrict__ Wcatb, u16* __restrict__ QcTb,
    u16* __restrict__ VcTb,  u16* __restrict__ Wob){
  int idx = blockIdx.x * 256 + threadIdx.x;
  if (idx < 720896){                       // 704*1024
    int r = idx >> 10, col = idx & 1023;
    float v;
    if (r < 64)       v = Wq[(size_t)r*1024 + col];
    else if (r < 128) v = Wk[(size_t)(r-64)*1024 + col];
    else if (r < 192) v = Wv[(size_t)(r-128)*1024 + col];
    else              v = Wa[(size_t)(r-192)*1024 + col];
    Wcatb[idx] = f2bf(v);
  } else if (idx < 753664){                // +512*64
    int i = idx - 720896;
    int n = i >> 6, c = i & 63; int h = n >> 6, e = n & 63;
    QcTb[i] = f2bf(Qc[((size_t)h*64 + c)*64 + e]);
  } else if (idx < 819200){                // +1024*64
    int i = idx - 753664;
    int n = i >> 6, c = i & 63; int h = n >> 7, d = n & 127;
    VcTb[i] = f2bf(Vc[((size_t)h*64 + c)*128 + d]);
  } else if (idx < 1867776){               // +1024*1024
    int i = idx - 819200;
    Wob[i] = f2bf(Wo[i]);
  }
}

// ------------- generic bf16 MFMA GEMM: C = A[M,K] @ Bw[N,K]^T (+res) -------
__global__ __launch_bounds__(256) void gemm_bf16(
    const u16* __restrict__ A, const u16* __restrict__ Bw,
    float* __restrict__ C, const float* __restrict__ res,
    u16* __restrict__ Cb, int N, int K){
  __shared__ u16 As[128][36];
  __shared__ u16 Bs[64][36];
  const int tid = threadIdx.x;
  const int wave = tid >> 6;
  const int lane = tid & 63;
  const int q  = lane >> 4;
  const int mr = lane & 15;
  const int m0 = blockIdx.x * 128;
  const int n0 = blockIdx.y * 64;

  union FragU { u32 u[4]; bf16x8 v; };
  f32x4 zero = {0.f, 0.f, 0.f, 0.f};
  f32x4 acc[2][4];
  #pragma unroll
  for (int i = 0; i < 2; i++)
    #pragma unroll
    for (int j = 0; j < 4; j++) acc[i][j] = zero;

  for (int k0 = 0; k0 < K; k0 += 32){
    #pragma unroll
    for (int p = 0; p < 2; ++p){
      int ch = p*256 + tid;
      int r = ch >> 2, c4 = ch & 3;
      const uint4 val = *(const uint4*)(&A[(size_t)(m0 + r)*K + k0 + c4*8]);
      u32* dst = (u32*)&As[r][c4*8];
      dst[0]=val.x; dst[1]=val.y; dst[2]=val.z; dst[3]=val.w;
    }
    {
      int r = tid >> 2, c4 = tid & 3;
      const uint4 val = *(const uint4*)(&Bw[(size_t)(n0 + r)*K + k0 + c4*8]);
      u32* dst = (u32*)&Bs[r][c4*8];
      dst[0]=val.x; dst[1]=val.y; dst[2]=val.z; dst[3]=val.w;
    }
    __syncthreads();
    bf16x8 afr[2], bfr[4];
    #pragma unroll
    for (int mt = 0; mt < 2; mt++){
      const u32* p = (const u32*)&As[wave*32 + mt*16 + mr][q*8];
      FragU f; f.u[0]=p[0]; f.u[1]=p[1]; f.u[2]=p[2]; f.u[3]=p[3];
      afr[mt] = f.v;
    }
    #pragma unroll
    for (int nt = 0; nt < 4; nt++){
      const u32* p = (const u32*)&Bs[nt*16 + mr][q*8];
      FragU f; f.u[0]=p[0]; f.u[1]=p[1]; f.u[2]=p[2]; f.u[3]=p[3];
      bfr[nt] = f.v;
    }
    #pragma unroll
    for (int mt = 0; mt < 2; mt++)
      #pragma unroll
      for (int nt = 0; nt < 4; nt++)
        acc[mt][nt] = __builtin_amdgcn_mfma_f32_16x16x32_bf16(
            afr[mt], bfr[nt], acc[mt][nt], 0, 0, 0);
    __syncthreads();
  }

  #pragma unroll
  for (int mt = 0; mt < 2; mt++)
    #pragma unroll
    for (int nt = 0; nt < 4; nt++)
      #pragma unroll
      for (int r = 0; r < 4; r++){
        int row = m0 + wave*32 + mt*16 + q*4 + r;
        int col = n0 + nt*16 + mr;
        size_t idx = (size_t)row * N + col;
        float v = acc[mt][nt][r];
        if (res) v += res[idx];
        if (Cb) Cb[idx] = f2bf(v);
        else    C[idx] = v;
      }
}

// ------------- split proj (M x 704) -------------
__global__ __launch_bounds__(256) void split_proj(
    const float* __restrict__ proj, const float* __restrict__ Wab,
    u16* __restrict__ qlatb, float* __restrict__ knf,
    u16* __restrict__ vlatb, float* __restrict__ alphaf){
  const int m = blockIdx.x * 4 + (threadIdx.x >> 6);
  const int lane = threadIdx.x & 63;
  const float* pr = proj + (size_t)m * 704;
  qlatb[(size_t)m*64 + lane] = f2bf(pr[lane]);
  float kv = pr[64 + lane];
  float ss = kv * kv;
  #pragma unroll
  for (int off = 32; off > 0; off >>= 1) ss += __shfl_xor(ss, off, 64);
  float nrm = fmaxf(sqrtf(ss), 1e-12f);
  knf[(size_t)m*64 + lane] = kv / nrm;
  vlatb[(size_t)m*64 + lane] = f2bf(pr[128 + lane]);
  #pragma unroll
  for (int j = 0; j < 8; j++){
    int jj = j*64 + lane;
    float av = pr[192 + jj] + Wab[jj];
    alphaf[(size_t)m*512 + jj] = 1.f / (1.f + expf(-av));
  }
}

// ===================== blocked two-pass gated scan =====================
// 512 threads: thread (g = tid>>7 in [0,4), d = tid&127). Each thread holds
// S[16] = state channels [g*16, g*16+16) for column d.  ~50 VGPRs -> no spill.
// pass1: per-chunk local scan from zero -> Sbuf[bh][ch][c][d], btot[bh][ch][c]
// combine: sequential over chunks, IN PLACE: Sbuf[ch] <- prefix state
// pass2: replay chunk scan from Sbuf, emit o (bf16) via LDS cross-g reduction

__global__ __launch_bounds__(512) void scan_pass1(
    const float* __restrict__ knf, const u16* __restrict__ vb,
    const float* __restrict__ alphaf,
    float* __restrict__ Sbuf, float* __restrict__ btot){
  const int ch = blockIdx.x;        // 0..NC_-2 (last chunk's state unused)
  const int bh = blockIdx.y;
  const int b = bh >> 3, h = bh & 7;
  const int tid = threadIdx.x;
  const int g = tid >> 7;           // channel group
  const int d = tid & 127;          // value column
  const int t0 = ch * L_;
  __shared__ __align__(16) float sK[TS_][64];
  __shared__ __align__(16) float sA[TS_][64];
  __shared__ __align__(16) float sV[TS_][128];

  const float* kbase = knf    + ((size_t)(b*T_ + t0))*64;
  const float* abase = alphaf + ((size_t)(b*T_ + t0))*512 + h*64;
  const u16*   vbase = vb     + ((size_t)(b*T_ + t0))*1024 + h*128;

  float S[16];
  #pragma unroll
  for (int i = 0; i < 16; i++) S[i] = 0.f;
  float bt = 1.f;

  const int ts = tid >> 6, cs = tid & 63;   // k/a staging: 8t x 64c
  for (int sb = 0; sb < L_/TS_; sb++){
    const int tb = sb * TS_;
    sK[ts][cs] = kbase[(size_t)(tb+ts)*64 + cs];
    sA[ts][cs] = abase[(size_t)(tb+ts)*512 + cs];
    {
      int i1 = 512 + tid;
      sV[tid>>7][tid&127] = bf2f(vbase[(size_t)(tb+(tid>>7))*1024 + (tid&127)]);
      sV[i1 >>7][i1 &127] = bf2f(vbase[(size_t)(tb+(i1 >>7))*1024 + (i1 &127)]);
    }
    __syncthreads();
    #pragma unroll
    for (int tt = 0; tt < TS_; tt++){
      const float vd = sV[tt][d];
      #pragma unroll
      for (int i4 = 0; i4 < 4; i4++){
        float4 a4 = *(const float4*)&sA[tt][g*16 + i4*4];
        float4 k4 = *(const float4*)&sK[tt][g*16 + i4*4];
        S[i4*4+0] = a4.x*S[i4*4+0] + k4.x*vd;
        S[i4*4+1] = a4.y*S[i4*4+1] + k4.y*vd;
        S[i4*4+2] = a4.z*S[i4*4+2] + k4.z*vd;
        S[i4*4+3] = a4.w*S[i4*4+3] + k4.w*vd;
      }
      if (d < 16) bt *= sA[tt][g*16 + d];
    }
    __syncthreads();
  }
  float* Sl = Sbuf + ((size_t)bh*NC_ + ch) * (64*128);
  #pragma unroll
  for (int i = 0; i < 16; i++) Sl[(size_t)(g*16+i)*128 + d] = S[i];
  if (d < 16) btot[((size_t)bh*NC_ + ch)*64 + g*16 + d] = bt;
}

// in-place: Sbuf[ch] (local states) -> Sbuf[ch] (prefix init states)
__global__ __launch_bounds__(256) void scan_combine(
    float* __restrict__ Sbuf, const float* __restrict__ btot){
  const int bh = blockIdx.x;
  const int tid = threadIdx.x;
  float S[32];
  #pragma unroll
  for (int i = 0; i < 32; i++) S[i] = 0.f;
  float*       Sb  = Sbuf + (size_t)bh*NC_*8192;
  const float* btb = btot + (size_t)bh*NC_*64;
  for (int j = 0; j < NC_; j++){
    if (j < NC_-1){
      #pragma unroll
      for (int i = 0; i < 32; i++){
        int e = i*256 + tid;
        float loc = Sb[(size_t)j*8192 + e];          // read local BEFORE overwrite
        float bv  = btb[j*64 + (e >> 7)];
        Sb[(size_t)j*8192 + e] = S[i];               // write prefix state
        S[i] = bv * S[i] + loc;
      }
    } else {
      #pragma unroll
      for (int i = 0; i < 32; i++) Sb[(size_t)j*8192 + i*256 + tid] = S[i];
    }
  }
}

__global__ __launch_bounds__(512) void scan_pass2(
    const float* __restrict__ qf, const float* __restrict__ knf,
    const u16* __restrict__ vb, const float* __restrict__ alphaf,
    const float* __restrict__ Sbuf, u16* __restrict__ ob){
  const int ch = blockIdx.x;        // 0..NC_-1
  const int bh = blockIdx.y;
  const int b = bh >> 3, h = bh & 7;
  const int tid = threadIdx.x;
  const int g = tid >> 7;
  const int d = tid & 127;
  const int t0 = ch * L_;
  __shared__ __align__(16) float sQ[TS_][64];
  __shared__ __align__(16) float sK[TS_][64];
  __shared__ __align__(16) float sA[TS_][64];
  __shared__ __align__(16) float sV[TS_][128];
  __shared__ __align__(16) float sO[4][TS_][128];

  const float* qbase = qf     + ((size_t)(b*T_ + t0))*512 + h*64;
  const float* kbase = knf    + ((size_t)(b*T_ + t0))*64;
  const float* abase = alphaf + ((size_t)(b*T_ + t0))*512 + h*64;
  const u16*   vbase = vb     + ((size_t)(b*T_ + t0))*1024 + h*128;
  u16*         obase = ob     + ((size_t)(b*T_ + t0))*1024 + h*128;

  float S[16];
  const float* Si = Sbuf + ((size_t)bh*NC_ + ch) * (64*128);
  #pragma unroll
  for (int i = 0; i < 16; i++) S[i] = Si[(size_t)(g*16+i)*128 + d];

  const int ts = tid >> 6, cs = tid & 63;
  for (int sb = 0; sb < L_/TS_; sb++){
    const int tb = sb * TS_;
    sQ[ts][cs] = qbase[(size_t)(tb+ts)*512 + cs];
    sK[ts][cs] = kbase[(size_t)(tb+ts)*64 + cs];
    sA[ts][cs] = abase[(size_t)(tb+ts)*512 + cs];
    {
      int i1 = 512 + tid;
      sV[tid>>7][tid&127] = bf2f(vbase[(size_t)(tb+(tid>>7))*1024 + (tid&127)]);
      sV[i1 >>7][i1 &127] = bf2f(vbase[(size_t)(tb+(i1 >>7))*1024 + (i1 &127)]);
    }
    __syncthreads();
    #pragma unroll
    for (int tt = 0; tt < TS_; tt++){
      const float vd = sV[tt][d];
      float o = 0.f;
      #pragma unroll
      for (int i4 = 0; i4 < 4; i4++){
        float4 a4 = *(const float4*)&sA[tt][g*16 + i4*4];
        float4 k4 = *(const float4*)&sK[tt][g*16 + i4*4];
        float4 q4 = *(const float4*)&sQ[tt][g*16 + i4*4];
        S[i4*4+0] = a4.x*S[i4*4+0] + k4.x*vd;  o += S[i4*4+0]*q4.x;
        S[i4*4+1] = a4.y*S[i4*4+1] + k4.y*vd;  o += S[i4*4+1]*q4.y;
        S[i4*4+2] = a4.z*S[i4*4+2] + k4.z*vd;  o += S[i4*4+2]*q4.z;
        S[i4*4+3] = a4.w*S[i4*4+3] + k4.w*vd;  o += S[i4*4+3]*q4.w;
      }
      sO[g][tt][d] = o;
    }
    __syncthreads();
    #pragma unroll
    for (int i = 0; i < 2; i++){
      int idx = i*512 + tid;
      int tt = idx >> 7, dd = idx & 127;
      float o = sO[0][tt][dd] + sO[1][tt][dd] + sO[2][tt][dd] + sO[3][tt][dd];
      obase[(size_t)(tb+tt)*1024 + dd] = f2bf(o);
    }
    // no extra barrier: next iteration's writes to sK/sA/sQ/sV don't alias sO,
    // and its sO writes happen only after the next __syncthreads().
  }
}

// ----------------------------- launch -----------------------------
extern "C" void kernel_launch(void* const* d_in, const int* in_sizes, int n_in,
                              void* d_out, int out_size, void* d_ws, size_t ws_size,
                              hipStream_t stream){
  const float* x     = (const float*)d_in[0];
  const float* Wq    = (const float*)d_in[1];
  const float* Wk    = (const float*)d_in[2];
  const float* Wv    = (const float*)d_in[3];
  const float* Qc    = (const float*)d_in[4];
  const float* Vc    = (const float*)d_in[5];
  const float* Wa_w  = (const float*)d_in[6];
  const float* Wa_b  = (const float*)d_in[7];
  const float* Wo    = (const float*)d_in[8];
  const float* gamma = (const float*)d_in[9];
  const float* beta  = (const float*)d_in[10];
  float* out = (float*)d_out;

  char* ws = (char*)d_ws;
  size_t off = 0;
  auto alloc = [&](size_t bytes) -> void* {
    void* p = ws + off; off += (bytes + 255) & ~(size_t)255; return p;
  };
  // total ws use: ~192.74 MB (round-1's 193.0 MB layout is proven to fit)
  // R1: xnb (bf16 M*1024) -> obuf (bf16 M*1024)
  char* R1 = (char*)alloc((size_t)M_ * 1024 * 2);
  u16*   xnb  = (u16*)R1;
  u16*   obuf = (u16*)R1;
  // R2: proj (f32 M*704) -> qf (f32 M*512)
  char* R2 = (char*)alloc((size_t)M_ * 704 * 4);
  float* proj = (float*)R2;
  float* qf   = (float*)R2;
  float* Sbuf   = (float*)alloc((size_t)64 * NC_ * 8192 * 4);   // 33.5 MB
  u16*   vfb    = (u16*)alloc((size_t)M_ * 1024 * 2);           // v bf16
  float* alphaf = (float*)alloc((size_t)M_ * 512 * 4);
  float* knf    = (float*)alloc((size_t)M_ * 64 * 4);
  u16*   qlatb  = (u16*)alloc((size_t)M_ * 64 * 2);
  u16*   vlatb  = (u16*)alloc((size_t)M_ * 64 * 2);
  u16*   Wcatb  = (u16*)alloc((size_t)704 * 1024 * 2);
  u16*   QcTb   = (u16*)alloc((size_t)512 * 64 * 2);
  u16*   VcTb   = (u16*)alloc((size_t)1024 * 64 * 2);
  u16*   Wob    = (u16*)alloc((size_t)1024 * 1024 * 2);
  float* btotp  = (float*)alloc((size_t)64 * NC_ * 64 * 4);
  (void)ws_size; (void)in_sizes; (void)n_in; (void)out_size;

  ln_kernel<<<dim3(M_), dim3(256), 0, stream>>>(x, gamma, beta, xnb);
  prep_weights<<<dim3(7296), dim3(256), 0, stream>>>(
      Wq, Wk, Wv, Wa_w, Qc, Vc, Wo, Wcatb, QcTb, VcTb, Wob);
  gemm_bf16<<<dim3(M_/128, 704/64), dim3(256), 0, stream>>>(
      xnb, Wcatb, proj, nullptr, nullptr, 704, 1024);
  split_proj<<<dim3(M_/4), dim3(256), 0, stream>>>(
      proj, Wa_b, qlatb, knf, vlatb, alphaf);
  // v = v_lat @ VcT^T : (M,1024) bf16 out
  gemm_bf16<<<dim3(M_/128, 1024/64), dim3(256), 0, stream>>>(
      vlatb, VcTb, nullptr, nullptr, vfb, 1024, 64);
  // q = q_lat @ QcT^T : (M,512) f32 into R2 (proj dead after split_proj)
  gemm_bf16<<<dim3(M_/128, 512/64), dim3(256), 0, stream>>>(
      qlatb, QcTb, qf, nullptr, nullptr, 512, 64);
  scan_pass1<<<dim3(NC_-1, 64), dim3(512), 0, stream>>>(
      knf, vfb, alphaf, Sbuf, btotp);
  scan_combine<<<dim3(64), dim3(256), 0, stream>>>(Sbuf, btotp);
  scan_pass2<<<dim3(NC_, 64), dim3(512), 0, stream>>>(
      qf, knf, vfb, alphaf, Sbuf, obuf);
  gemm_bf16<<<dim3(M_/128, 1024/64), dim3(256), 0, stream>>>(
      obuf, Wob, out, x, nullptr, 1024, 1024);
}

// Round 5
// 567.591 us; speedup vs baseline: 4.6803x; 1.5420x over previous
//
#include <hip/hip_runtime.h>

typedef unsigned short u16;
typedef unsigned int   u32;
typedef __bf16 bf16x8 __attribute__((ext_vector_type(8)));
typedef float  f32x4  __attribute__((ext_vector_type(4)));

#define B_  8
#define T_  2048
#define D_  1024
#define H_  8
#define C_  64
#define DV_ 128
#define M_  (B_*T_)   // 16384
#define L_  128       // scan chunk length
#define NC_ (T_/L_)   // 16 chunks
#define TS_ 8         // timesteps per LDS sub-block

__device__ __forceinline__ u16 f2bf(float f){
  u32 u = __float_as_uint(f);
  u32 r = (u + 0x7fffu + ((u >> 16) & 1u)) >> 16;   // RNE
  return (u16)r;
}
__device__ __forceinline__ float bf2f(u16 u){
  return __uint_as_float(((u32)u) << 16);
}

// ---------------- LayerNorm: x (M,1024) f32 -> xn bf16 ----------------
__global__ __launch_bounds__(256) void ln_kernel(
    const float* __restrict__ x, const float* __restrict__ gamma,
    const float* __restrict__ beta, u16* __restrict__ xnb){
  const int m = blockIdx.x;
  const int tid = threadIdx.x;
  const int wave = tid >> 6, lane = tid & 63;
  const float* xr = x + (size_t)m * D_;
  float4 xv = *(const float4*)&xr[tid*4];
  float s = xv.x + xv.y + xv.z + xv.w;
  #pragma unroll
  for (int off = 32; off > 0; off >>= 1) s += __shfl_xor(s, off, 64);
  __shared__ float red[8];
  if (lane == 0) red[wave] = s;
  __syncthreads();
  float mu = (red[0]+red[1]+red[2]+red[3]) * (1.f/1024.f);
  float dx = xv.x-mu, dy = xv.y-mu, dz = xv.z-mu, dw = xv.w-mu;
  float ss = dx*dx + dy*dy + dz*dz + dw*dw;
  #pragma unroll
  for (int off = 32; off > 0; off >>= 1) ss += __shfl_xor(ss, off, 64);
  if (lane == 0) red[4+wave] = ss;
  __syncthreads();
  float var = (red[4]+red[5]+red[6]+red[7]) * (1.f/1024.f);
  float rs = rsqrtf(var + 1e-5f);
  float4 g  = *(const float4*)&gamma[tid*4];
  float4 bb = *(const float4*)&beta[tid*4];
  ushort4 o4;
  o4.x = f2bf(dx*rs*g.x + bb.x);
  o4.y = f2bf(dy*rs*g.y + bb.y);
  o4.z = f2bf(dz*rs*g.z + bb.z);
  o4.w = f2bf(dw*rs*g.w + bb.w);
  *(ushort4*)&xnb[(size_t)m*D_ + tid*4] = o4;
}

// ------------- weight prep: convert/concat/transpose to bf16 -------------
__global__ __launch_bounds__(256) void prep_weights(
    const float* __restrict__ Wq, const float* __restrict__ Wk,
    const float* __restrict__ Wv, const float* __restrict__ Wa,
    const float* __restrict__ Qc, const float* __restrict__ Vc,
    const float* __restrict__ Wo,
    u16* __restrict__ Wcatb, u16* __restrict__ QcTb,
    u16* __restrict__ VcTb,  u16* __restrict__ Wob){
  int idx = blockIdx.x * 256 + threadIdx.x;
  if (idx < 720896){                       // 704*1024
    int r = idx >> 10, col = idx & 1023;
    float v;
    if (r < 64)       v = Wq[(size_t)r*1024 + col];
    else if (r < 128) v = Wk[(size_t)(r-64)*1024 + col];
    else if (r < 192) v = Wv[(size_t)(r-128)*1024 + col];
    else              v = Wa[(size_t)(r-192)*1024 + col];
    Wcatb[idx] = f2bf(v);
  } else if (idx < 753664){                // +512*64
    int i = idx - 720896;
    int n = i >> 6, c = i & 63; int h = n >> 6, e = n & 63;
    QcTb[i] = f2bf(Qc[((size_t)h*64 + c)*64 + e]);
  } else if (idx < 819200){                // +1024*64
    int i = idx - 753664;
    int n = i >> 6, c = i & 63; int h = n >> 7, d = n & 127;
    VcTb[i] = f2bf(Vc[((size_t)h*64 + c)*128 + d]);
  } else if (idx < 1867776){               // +1024*1024
    int i = idx - 819200;
    Wob[i] = f2bf(Wo[i]);
  }
}

// ------------- generic bf16 MFMA GEMM: C = A[M,K] @ Bw[N,K]^T (+res) -------
__global__ __launch_bounds__(256) void gemm_bf16(
    const u16* __restrict__ A, const u16* __restrict__ Bw,
    float* __restrict__ C, const float* __restrict__ res,
    u16* __restrict__ Cb, int N, int K){
  __shared__ u16 As[128][36];
  __shared__ u16 Bs[64][36];
  const int tid = threadIdx.x;
  const int wave = tid >> 6;
  const int lane = tid & 63;
  const int q  = lane >> 4;
  const int mr = lane & 15;
  const int m0 = blockIdx.x * 128;
  const int n0 = blockIdx.y * 64;

  union FragU { u32 u[4]; bf16x8 v; };
  f32x4 zero = {0.f, 0.f, 0.f, 0.f};
  f32x4 acc[2][4];
  #pragma unroll
  for (int i = 0; i < 2; i++)
    #pragma unroll
    for (int j = 0; j < 4; j++) acc[i][j] = zero;

  for (int k0 = 0; k0 < K; k0 += 32){
    #pragma unroll
    for (int p = 0; p < 2; ++p){
      int ch = p*256 + tid;
      int r = ch >> 2, c4 = ch & 3;
      const uint4 val = *(const uint4*)(&A[(size_t)(m0 + r)*K + k0 + c4*8]);
      u32* dst = (u32*)&As[r][c4*8];
      dst[0]=val.x; dst[1]=val.y; dst[2]=val.z; dst[3]=val.w;
    }
    {
      int r = tid >> 2, c4 = tid & 3;
      const uint4 val = *(const uint4*)(&Bw[(size_t)(n0 + r)*K + k0 + c4*8]);
      u32* dst = (u32*)&Bs[r][c4*8];
      dst[0]=val.x; dst[1]=val.y; dst[2]=val.z; dst[3]=val.w;
    }
    __syncthreads();
    bf16x8 afr[2], bfr[4];
    #pragma unroll
    for (int mt = 0; mt < 2; mt++){
      const u32* p = (const u32*)&As[wave*32 + mt*16 + mr][q*8];
      FragU f; f.u[0]=p[0]; f.u[1]=p[1]; f.u[2]=p[2]; f.u[3]=p[3];
      afr[mt] = f.v;
    }
    #pragma unroll
    for (int nt = 0; nt < 4; nt++){
      const u32* p = (const u32*)&Bs[nt*16 + mr][q*8];
      FragU f; f.u[0]=p[0]; f.u[1]=p[1]; f.u[2]=p[2]; f.u[3]=p[3];
      bfr[nt] = f.v;
    }
    #pragma unroll
    for (int mt = 0; mt < 2; mt++)
      #pragma unroll
      for (int nt = 0; nt < 4; nt++)
        acc[mt][nt] = __builtin_amdgcn_mfma_f32_16x16x32_bf16(
            afr[mt], bfr[nt], acc[mt][nt], 0, 0, 0);
    __syncthreads();
  }

  #pragma unroll
  for (int mt = 0; mt < 2; mt++)
    #pragma unroll
    for (int nt = 0; nt < 4; nt++)
      #pragma unroll
      for (int r = 0; r < 4; r++){
        int row = m0 + wave*32 + mt*16 + q*4 + r;
        int col = n0 + nt*16 + mr;
        size_t idx = (size_t)row * N + col;
        float v = acc[mt][nt][r];
        if (res) v += res[idx];
        if (Cb) Cb[idx] = f2bf(v);
        else    C[idx] = v;
      }
}

// ------------- split proj (M x 704) -------------
__global__ __launch_bounds__(256) void split_proj(
    const float* __restrict__ proj, const float* __restrict__ Wab,
    u16* __restrict__ qlatb, float* __restrict__ knf,
    u16* __restrict__ vlatb, float* __restrict__ alphaf){
  const int m = blockIdx.x * 4 + (threadIdx.x >> 6);
  const int lane = threadIdx.x & 63;
  const float* pr = proj + (size_t)m * 704;
  qlatb[(size_t)m*64 + lane] = f2bf(pr[lane]);
  float kv = pr[64 + lane];
  float ss = kv * kv;
  #pragma unroll
  for (int off = 32; off > 0; off >>= 1) ss += __shfl_xor(ss, off, 64);
  float nrm = fmaxf(sqrtf(ss), 1e-12f);
  knf[(size_t)m*64 + lane] = kv / nrm;
  vlatb[(size_t)m*64 + lane] = f2bf(pr[128 + lane]);
  #pragma unroll
  for (int j = 0; j < 8; j++){
    int jj = j*64 + lane;
    float av = pr[192 + jj] + Wab[jj];
    alphaf[(size_t)m*512 + jj] = 1.f / (1.f + expf(-av));
  }
}

// ===================== blocked two-pass gated scan =====================
// 512 threads: thread (g = tid>>7 in [0,4), d = tid&127). Each thread holds
// S[16] = state channels [g*16, g*16+16) for column d.
// ANTI-SPILL: tt loop is unroll-1 with a sched_barrier each iteration —
// round-4 showed the fully-unrolled loop hoists 8 timesteps of ds_read_b128
// (hundreds of live VGPRs) and spills S to scratch (1.19 GB HBM writes).
// __launch_bounds__(512,2) raises the VGPR cap to 256 as a backstop.

__global__ __launch_bounds__(512, 2) void scan_pass1(
    const float* __restrict__ knf, const u16* __restrict__ vb,
    const float* __restrict__ alphaf,
    float* __restrict__ Sbuf, float* __restrict__ btot){
  const int ch = blockIdx.x;        // 0..NC_-2 (last chunk's state unused)
  const int bh = blockIdx.y;
  const int b = bh >> 3, h = bh & 7;
  const int tid = threadIdx.x;
  const int g = tid >> 7;           // channel group
  const int d = tid & 127;          // value column
  const int t0 = ch * L_;
  __shared__ __align__(16) float sK[TS_][64];
  __shared__ __align__(16) float sA[TS_][64];
  __shared__ __align__(16) float sV[TS_][128];

  const float* kbase = knf    + ((size_t)(b*T_ + t0))*64;
  const float* abase = alphaf + ((size_t)(b*T_ + t0))*512 + h*64;
  const u16*   vbase = vb     + ((size_t)(b*T_ + t0))*1024 + h*128;

  float S[16];
  #pragma unroll
  for (int i = 0; i < 16; i++) S[i] = 0.f;
  float bt = 1.f;

  const int ts = tid >> 6, cs = tid & 63;   // k/a staging: 8t x 64c
  for (int sb = 0; sb < L_/TS_; sb++){
    const int tb = sb * TS_;
    sK[ts][cs] = kbase[(size_t)(tb+ts)*64 + cs];
    sA[ts][cs] = abase[(size_t)(tb+ts)*512 + cs];
    {
      int i1 = 512 + tid;
      sV[tid>>7][tid&127] = bf2f(vbase[(size_t)(tb+(tid>>7))*1024 + (tid&127)]);
      sV[i1 >>7][i1 &127] = bf2f(vbase[(size_t)(tb+(i1 >>7))*1024 + (i1 &127)]);
    }
    __syncthreads();
    #pragma unroll 1
    for (int tt = 0; tt < TS_; tt++){
      const float vd = sV[tt][d];
      #pragma unroll
      for (int i4 = 0; i4 < 4; i4++){
        float4 a4 = *(const float4*)&sA[tt][g*16 + i4*4];
        float4 k4 = *(const float4*)&sK[tt][g*16 + i4*4];
        S[i4*4+0] = a4.x*S[i4*4+0] + k4.x*vd;
        S[i4*4+1] = a4.y*S[i4*4+1] + k4.y*vd;
        S[i4*4+2] = a4.z*S[i4*4+2] + k4.z*vd;
        S[i4*4+3] = a4.w*S[i4*4+3] + k4.w*vd;
      }
      if (d < 16) bt *= sA[tt][g*16 + d];
      __builtin_amdgcn_sched_barrier(0);   // stop cross-tt LDS-load hoisting
    }
    __syncthreads();
  }
  float* Sl = Sbuf + ((size_t)bh*NC_ + ch) * (64*128);
  #pragma unroll
  for (int i = 0; i < 16; i++) Sl[(size_t)(g*16+i)*128 + d] = S[i];
  if (d < 16) btot[((size_t)bh*NC_ + ch)*64 + g*16 + d] = bt;
}

// in-place: Sbuf[ch] (local states) -> Sbuf[ch] (prefix init states)
__global__ __launch_bounds__(256) void scan_combine(
    float* __restrict__ Sbuf, const float* __restrict__ btot){
  const int bh = blockIdx.x;
  const int tid = threadIdx.x;
  float S[32];
  #pragma unroll
  for (int i = 0; i < 32; i++) S[i] = 0.f;
  float*       Sb  = Sbuf + (size_t)bh*NC_*8192;
  const float* btb = btot + (size_t)bh*NC_*64;
  for (int j = 0; j < NC_; j++){
    if (j < NC_-1){
      #pragma unroll
      for (int i = 0; i < 32; i++){
        int e = i*256 + tid;
        float loc = Sb[(size_t)j*8192 + e];          // read local BEFORE overwrite
        float bv  = btb[j*64 + (e >> 7)];
        Sb[(size_t)j*8192 + e] = S[i];               // write prefix state
        S[i] = bv * S[i] + loc;
      }
    } else {
      #pragma unroll
      for (int i = 0; i < 32; i++) Sb[(size_t)j*8192 + i*256 + tid] = S[i];
    }
  }
}

__global__ __launch_bounds__(512, 2) void scan_pass2(
    const float* __restrict__ qf, const float* __restrict__ knf,
    const u16* __restrict__ vb, const float* __restrict__ alphaf,
    const float* __restrict__ Sbuf, u16* __restrict__ ob){
  const int ch = blockIdx.x;        // 0..NC_-1
  const int bh = blockIdx.y;
  const int b = bh >> 3, h = bh & 7;
  const int tid = threadIdx.x;
  const int g = tid >> 7;
  const int d = tid & 127;
  const int t0 = ch * L_;
  __shared__ __align__(16) float sQ[TS_][64];
  __shared__ __align__(16) float sK[TS_][64];
  __shared__ __align__(16) float sA[TS_][64];
  __shared__ __align__(16) float sV[TS_][128];
  __shared__ __align__(16) float sO[4][TS_][128];

  const float* qbase = qf     + ((size_t)(b*T_ + t0))*512 + h*64;
  const float* kbase = knf    + ((size_t)(b*T_ + t0))*64;
  const float* abase = alphaf + ((size_t)(b*T_ + t0))*512 + h*64;
  const u16*   vbase = vb     + ((size_t)(b*T_ + t0))*1024 + h*128;
  u16*         obase = ob     + ((size_t)(b*T_ + t0))*1024 + h*128;

  float S[16];
  const float* Si = Sbuf + ((size_t)bh*NC_ + ch) * (64*128);
  #pragma unroll
  for (int i = 0; i < 16; i++) S[i] = Si[(size_t)(g*16+i)*128 + d];

  const int ts = tid >> 6, cs = tid & 63;
  for (int sb = 0; sb < L_/TS_; sb++){
    const int tb = sb * TS_;
    sQ[ts][cs] = qbase[(size_t)(tb+ts)*512 + cs];
    sK[ts][cs] = kbase[(size_t)(tb+ts)*64 + cs];
    sA[ts][cs] = abase[(size_t)(tb+ts)*512 + cs];
    {
      int i1 = 512 + tid;
      sV[tid>>7][tid&127] = bf2f(vbase[(size_t)(tb+(tid>>7))*1024 + (tid&127)]);
      sV[i1 >>7][i1 &127] = bf2f(vbase[(size_t)(tb+(i1 >>7))*1024 + (i1 &127)]);
    }
    __syncthreads();
    #pragma unroll 1
    for (int tt = 0; tt < TS_; tt++){
      const float vd = sV[tt][d];
      float o = 0.f;
      #pragma unroll
      for (int i4 = 0; i4 < 4; i4++){
        float4 a4 = *(const float4*)&sA[tt][g*16 + i4*4];
        float4 k4 = *(const float4*)&sK[tt][g*16 + i4*4];
        float4 q4 = *(const float4*)&sQ[tt][g*16 + i4*4];
        S[i4*4+0] = a4.x*S[i4*4+0] + k4.x*vd;  o += S[i4*4+0]*q4.x;
        S[i4*4+1] = a4.y*S[i4*4+1] + k4.y*vd;  o += S[i4*4+1]*q4.y;
        S[i4*4+2] = a4.z*S[i4*4+2] + k4.z*vd;  o += S[i4*4+2]*q4.z;
        S[i4*4+3] = a4.w*S[i4*4+3] + k4.w*vd;  o += S[i4*4+3]*q4.w;
      }
      sO[g][tt][d] = o;
      __builtin_amdgcn_sched_barrier(0);   // stop cross-tt LDS-load hoisting
    }
    __syncthreads();
    #pragma unroll
    for (int i = 0; i < 2; i++){
      int idx = i*512 + tid;
      int tt = idx >> 7, dd = idx & 127;
      float o = sO[0][tt][dd] + sO[1][tt][dd] + sO[2][tt][dd] + sO[3][tt][dd];
      obase[(size_t)(tb+tt)*1024 + dd] = f2bf(o);
    }
    // no extra barrier: next iteration's writes to sK/sA/sQ/sV don't alias sO,
    // and its sO writes happen only after the next __syncthreads().
  }
}

// ----------------------------- launch -----------------------------
extern "C" void kernel_launch(void* const* d_in, const int* in_sizes, int n_in,
                              void* d_out, int out_size, void* d_ws, size_t ws_size,
                              hipStream_t stream){
  const float* x     = (const float*)d_in[0];
  const float* Wq    = (const float*)d_in[1];
  const float* Wk    = (const float*)d_in[2];
  const float* Wv    = (const float*)d_in[3];
  const float* Qc    = (const float*)d_in[4];
  const float* Vc    = (const float*)d_in[5];
  const float* Wa_w  = (const float*)d_in[6];
  const float* Wa_b  = (const float*)d_in[7];
  const float* Wo    = (const float*)d_in[8];
  const float* gamma = (const float*)d_in[9];
  const float* beta  = (const float*)d_in[10];
  float* out = (float*)d_out;

  char* ws = (char*)d_ws;
  size_t off = 0;
  auto alloc = [&](size_t bytes) -> void* {
    void* p = ws + off; off += (bytes + 255) & ~(size_t)255; return p;
  };
  // total ws use: ~192.74 MB (round-1's 193.0 MB layout is proven to fit)
  // R1: xnb (bf16 M*1024) -> obuf (bf16 M*1024)
  char* R1 = (char*)alloc((size_t)M_ * 1024 * 2);
  u16*   xnb  = (u16*)R1;
  u16*   obuf = (u16*)R1;
  // R2: proj (f32 M*704) -> qf (f32 M*512)
  char* R2 = (char*)alloc((size_t)M_ * 704 * 4);
  float* proj = (float*)R2;
  float* qf   = (float*)R2;
  float* Sbuf   = (float*)alloc((size_t)64 * NC_ * 8192 * 4);   // 33.5 MB
  u16*   vfb    = (u16*)alloc((size_t)M_ * 1024 * 2);           // v bf16
  float* alphaf = (float*)alloc((size_t)M_ * 512 * 4);
  float* knf    = (float*)alloc((size_t)M_ * 64 * 4);
  u16*   qlatb  = (u16*)alloc((size_t)M_ * 64 * 2);
  u16*   vlatb  = (u16*)alloc((size_t)M_ * 64 * 2);
  u16*   Wcatb  = (u16*)alloc((size_t)704 * 1024 * 2);
  u16*   QcTb   = (u16*)alloc((size_t)512 * 64 * 2);
  u16*   VcTb   = (u16*)alloc((size_t)1024 * 64 * 2);
  u16*   Wob    = (u16*)alloc((size_t)1024 * 1024 * 2);
  float* btotp  = (float*)alloc((size_t)64 * NC_ * 64 * 4);
  (void)ws_size; (void)in_sizes; (void)n_in; (void)out_size;

  ln_kernel<<<dim3(M_), dim3(256), 0, stream>>>(x, gamma, beta, xnb);
  prep_weights<<<dim3(7296), dim3(256), 0, stream>>>(
      Wq, Wk, Wv, Wa_w, Qc, Vc, Wo, Wcatb, QcTb, VcTb, Wob);
  gemm_bf16<<<dim3(M_/128, 704/64), dim3(256), 0, stream>>>(
      xnb, Wcatb, proj, nullptr, nullptr, 704, 1024);
  split_proj<<<dim3(M_/4), dim3(256), 0, stream>>>(
      proj, Wa_b, qlatb, knf, vlatb, alphaf);
  // v = v_lat @ VcT^T : (M,1024) bf16 out
  gemm_bf16<<<dim3(M_/128, 1024/64), dim3(256), 0, stream>>>(
      vlatb, VcTb, nullptr, nullptr, vfb, 1024, 64);
  // q = q_lat @ QcT^T : (M,512) f32 into R2 (proj dead after split_proj)
  gemm_bf16<<<dim3(M_/128, 512/64), dim3(256), 0, stream>>>(
      qlatb, QcTb, qf, nullptr, nullptr, 512, 64);
  scan_pass1<<<dim3(NC_-1, 64), dim3(512), 0, stream>>>(
      knf, vfb, alphaf, Sbuf, btotp);
  scan_combine<<<dim3(64), dim3(256), 0, stream>>>(Sbuf, btotp);
  scan_pass2<<<dim3(NC_, 64), dim3(512), 0, stream>>>(
      qf, knf, vfb, alphaf, Sbuf, obuf);
  gemm_bf16<<<dim3(M_/128, 1024/64), dim3(256), 0, stream>>>(
      obuf, Wob, out, x, nullptr, 1024, 1024);
}